// Round 3
// baseline (135.018 us; speedup 1.0000x reference)
//
#include <hip/hip_runtime.h>
#include <math.h>

#define BLOCK 256
#define NBLOCKS 2048

// Each thread owns 4 consecutive frames:
//   rot  data: 4*9  = 36 floats = 144 B = 9 aligned float4
//   pose data: 4*3  = 12 floats =  48 B = 3 aligned float4
// -> 24 independent vector loads per thread, no LDS, no barriers.

__global__ __launch_bounds__(BLOCK, 4) void rmse_partial_kernel(
    const float* __restrict__ rot_kf, const float* __restrict__ pose_kf,
    const float* __restrict__ rot_gt, const float* __restrict__ pose_gt,
    float* __restrict__ partial, int N)
{
    __shared__ float redbuf[BLOCK / 64];

    const int tid = threadIdx.x;
    const int G = (N + 3) >> 2;                 // groups of 4 frames
    const int stride = gridDim.x * BLOCK;

    float sum = 0.0f;

    for (int g = blockIdx.x * BLOCK + tid; g < G; g += stride) {
        const int f0 = g << 2;

        float Af[36], Bf[36], Pk[12], Pg[12];

        if (f0 + 3 < N) {
            const float4* a4  = reinterpret_cast<const float4*>(rot_kf)  + (long long)g * 9;
            const float4* b4  = reinterpret_cast<const float4*>(rot_gt)  + (long long)g * 9;
            const float4* pk4 = reinterpret_cast<const float4*>(pose_kf) + (long long)g * 3;
            const float4* pg4 = reinterpret_cast<const float4*>(pose_gt) + (long long)g * 3;
            #pragma unroll
            for (int j = 0; j < 9; ++j) {
                const float4 v = a4[j];
                Af[4*j] = v.x; Af[4*j+1] = v.y; Af[4*j+2] = v.z; Af[4*j+3] = v.w;
            }
            #pragma unroll
            for (int j = 0; j < 9; ++j) {
                const float4 v = b4[j];
                Bf[4*j] = v.x; Bf[4*j+1] = v.y; Bf[4*j+2] = v.z; Bf[4*j+3] = v.w;
            }
            #pragma unroll
            for (int j = 0; j < 3; ++j) {
                const float4 u = pk4[j];
                Pk[4*j] = u.x; Pk[4*j+1] = u.y; Pk[4*j+2] = u.z; Pk[4*j+3] = u.w;
                const float4 w = pg4[j];
                Pg[4*j] = w.x; Pg[4*j+1] = w.y; Pg[4*j+2] = w.z; Pg[4*j+3] = w.w;
            }
            #pragma unroll
            for (int s = 0; s < 4; ++s) {
                const float* a = &Af[s * 9];
                const float* b = &Bf[s * 9];
                const float d0 = Pg[s*3+0] - Pk[s*3+0];
                const float d1 = Pg[s*3+1] - Pk[s*3+1];
                const float d2 = Pg[s*3+2] - Pk[s*3+2];
                float se = 0.0f;
                #pragma unroll
                for (int i = 0; i < 3; ++i) {
                    #pragma unroll
                    for (int k = 0; k < 3; ++k) {
                        float r = a[i] * b[k] + a[3+i] * b[3+k] + a[6+i] * b[6+k];
                        r -= (i == k) ? 1.0f : 0.0f;
                        se += r * r;
                    }
                    const float t = a[i] * d0 + a[3+i] * d1 + a[6+i] * d2;
                    se += t * t;
                }
                sum += se;
            }
        } else {
            // ragged tail group: scalar per-frame path
            for (int f = f0; f < N; ++f) {
                float a[9], b[9];
                #pragma unroll
                for (int j = 0; j < 9; ++j) {
                    a[j] = rot_kf[(long long)f * 9 + j];
                    b[j] = rot_gt[(long long)f * 9 + j];
                }
                const long long p = (long long)f * 3;
                const float d0 = pose_gt[p+0] - pose_kf[p+0];
                const float d1 = pose_gt[p+1] - pose_kf[p+1];
                const float d2 = pose_gt[p+2] - pose_kf[p+2];
                float se = 0.0f;
                #pragma unroll
                for (int i = 0; i < 3; ++i) {
                    #pragma unroll
                    for (int k = 0; k < 3; ++k) {
                        float r = a[i] * b[k] + a[3+i] * b[3+k] + a[6+i] * b[6+k];
                        r -= (i == k) ? 1.0f : 0.0f;
                        se += r * r;
                    }
                    const float t = a[i] * d0 + a[3+i] * d1 + a[6+i] * d2;
                    se += t * t;
                }
                sum += se;
            }
        }
    }

    // ---- block reduction ----
    const int lane = tid & 63;
    const int wave = tid >> 6;
    #pragma unroll
    for (int off = 32; off > 0; off >>= 1) sum += __shfl_down(sum, off);
    if (lane == 0) redbuf[wave] = sum;
    __syncthreads();
    if (tid == 0) {
        float s = 0.0f;
        #pragma unroll
        for (int w = 0; w < BLOCK / 64; ++w) s += redbuf[w];
        partial[blockIdx.x] = s;
    }
}

__global__ __launch_bounds__(BLOCK) void rmse_finalize_kernel(
    const float* __restrict__ partial, int nPartial, float* __restrict__ out, int N)
{
    __shared__ float redbuf[BLOCK / 64];
    float sum = 0.0f;
    for (int i = threadIdx.x; i < nPartial; i += BLOCK) sum += partial[i];
    #pragma unroll
    for (int off = 32; off > 0; off >>= 1) sum += __shfl_down(sum, off);
    const int lane = threadIdx.x & 63;
    const int wave = threadIdx.x >> 6;
    if (lane == 0) redbuf[wave] = sum;
    __syncthreads();
    if (threadIdx.x == 0) {
        float s = 0.0f;
        #pragma unroll
        for (int w = 0; w < BLOCK / 64; ++w) s += redbuf[w];
        out[0] = sqrtf(s / (float)N) + 1e-8f;
    }
}

extern "C" void kernel_launch(void* const* d_in, const int* in_sizes, int n_in,
                              void* d_out, int out_size, void* d_ws, size_t ws_size,
                              hipStream_t stream) {
    const float* rot_kf  = (const float*)d_in[0];
    const float* pose_kf = (const float*)d_in[1];
    const float* rot_gt  = (const float*)d_in[2];
    const float* pose_gt = (const float*)d_in[3];
    float* out = (float*)d_out;
    float* partial = (float*)d_ws;

    const int N = in_sizes[1] / 3;   // pose_kf is [N,3]
    const int G = (N + 3) >> 2;
    const int nBlocksNeeded = (G + BLOCK - 1) / BLOCK;

    int grid = NBLOCKS;
    if (grid > nBlocksNeeded) grid = nBlocksNeeded;
    const int wsCap = (int)(ws_size / sizeof(float));
    if (grid > wsCap) grid = wsCap;
    if (grid < 1) grid = 1;

    rmse_partial_kernel<<<grid, BLOCK, 0, stream>>>(rot_kf, pose_kf, rot_gt, pose_gt, partial, N);
    rmse_finalize_kernel<<<1, BLOCK, 0, stream>>>(partial, grid, out, N);
}

// Round 4
// 74.899 us; speedup vs baseline: 1.8027x; 1.8027x over previous
//
#include <hip/hip_runtime.h>
#include <math.h>

#define BLOCK 256
#define FPT   4                    // frames per thread per chunk
#define FPC   1024                 // frames per chunk
#define F4_PER_STAGE 2304          // FPC*9/4 float4 per rot array per chunk (9 per thread)
#define MAXBLOCKS 2048

// Direct global->LDS async copy, 16B per lane. LDS dest must be
// wave-uniform base + lane*16 — our layout (j*BLOCK+tid)*16B satisfies this.
#define GLOAD_LDS16(gp, lp)                                                     \
  __builtin_amdgcn_global_load_lds(                                             \
      (const __attribute__((address_space(1))) void*)(gp),                      \
      (__attribute__((address_space(3))) void*)(lp), 16, 0, 0)

__global__ __launch_bounds__(BLOCK, 2) void rmse_partial_kernel(
    const float* __restrict__ rot_kf, const float* __restrict__ pose_kf,
    const float* __restrict__ rot_gt, const float* __restrict__ pose_gt,
    float* __restrict__ partial, int N)
{
    // ring-2: lds[0] holds A-stage (rot_kf chunk), lds[1] holds B-stage (rot_gt chunk)
    __shared__ float lds[2][FPC * 9];        // 2 x 36864 B
    __shared__ float redbuf[BLOCK / 64];

    const int tid = threadIdx.x;
    const long long totalRotF = (long long)N * 9;
    const long long f4max = (totalRotF >= 4) ? (totalRotF - 4) / 4 : 0; // last fully in-bounds float4
    const int nChunks = (int)(((long long)N + FPC - 1) / FPC);
    const int stride = gridDim.x;

    float sum = 0.0f;

    // issue one stage: 9 global_load_lds_dwordx4 per thread, contiguous per wave
    auto issue = [&](const float* __restrict__ src, float* ldsBuf, int cc) {
        const long long base4 = (long long)cc * F4_PER_STAGE;
        #pragma unroll
        for (int j = 0; j < 9; ++j) {
            long long f4 = base4 + j * BLOCK + tid;
            if (f4 > f4max) f4 = f4max;          // tail clamp (garbage masked in compute)
            GLOAD_LDS16(reinterpret_cast<const float4*>(src) + f4,
                        ldsBuf + (size_t)(j * BLOCK + tid) * 4);
        }
    };

    int c = blockIdx.x;
    if (c < nChunks) {
        issue(rot_kf, lds[0], c);     // A(c)  : 9 in flight
        issue(rot_gt, lds[1], c);     // B(c)  : 18 in flight
    }

    while (c < nChunks) {
        const int cn = c + stride;
        const bool hasNext = (cn < nChunks);

        // ---- A phase: consume A(c) from lds[0]; B(c) stays in flight ----
        asm volatile("s_waitcnt vmcnt(9)" ::: "memory");   // A(c) landed
        __builtin_amdgcn_sched_barrier(0);
        __builtin_amdgcn_s_barrier();

        float a[FPT][9];
        #pragma unroll
        for (int s = 0; s < FPT; ++s) {
            #pragma unroll
            for (int j = 0; j < 9; ++j) a[s][j] = lds[0][(s * BLOCK + tid) * 9 + j];
        }
        asm volatile("s_waitcnt lgkmcnt(0)" ::: "memory"); // my reads done before re-stage
        __builtin_amdgcn_sched_barrier(0);
        __builtin_amdgcn_s_barrier();
        if (hasNext) issue(rot_kf, lds[0], cn);            // A(cn) in flight

        // ---- B phase: consume B(c) from lds[1]; A(cn) stays in flight ----
        if (hasNext) { asm volatile("s_waitcnt vmcnt(9)" ::: "memory"); }
        else         { asm volatile("s_waitcnt vmcnt(0)" ::: "memory"); }
        __builtin_amdgcn_sched_barrier(0);
        __builtin_amdgcn_s_barrier();

        #pragma unroll
        for (int s = 0; s < FPT; ++s) {
            const int frame = c * FPC + s * BLOCK + tid;
            if (frame < N) {
                float b[9];
                #pragma unroll
                for (int j = 0; j < 9; ++j) b[j] = lds[1][(s * BLOCK + tid) * 9 + j];

                const long long p = (long long)frame * 3;
                const float d0 = pose_gt[p + 0] - pose_kf[p + 0];
                const float d1 = pose_gt[p + 1] - pose_kf[p + 1];
                const float d2 = pose_gt[p + 2] - pose_kf[p + 2];

                float se = 0.0f;
                #pragma unroll
                for (int i = 0; i < 3; ++i) {
                    #pragma unroll
                    for (int k = 0; k < 3; ++k) {
                        // R_rel[i][k] = sum_j A[j][i]*B[j][k]
                        float r = a[s][i] * b[k] + a[s][3 + i] * b[3 + k] + a[s][6 + i] * b[6 + k];
                        r -= (i == k) ? 1.0f : 0.0f;
                        se += r * r;
                    }
                    const float t = a[s][i] * d0 + a[s][3 + i] * d1 + a[s][6 + i] * d2;
                    se += t * t;
                }
                sum += se;
            }
        }
        asm volatile("s_waitcnt lgkmcnt(0)" ::: "memory");
        __builtin_amdgcn_sched_barrier(0);
        __builtin_amdgcn_s_barrier();
        if (hasNext) issue(rot_gt, lds[1], cn);            // B(cn) in flight

        c = cn;
    }

    // ---- block reduction (full __syncthreads is fine here, once) ----
    const int lane = tid & 63;
    const int wave = tid >> 6;
    #pragma unroll
    for (int off = 32; off > 0; off >>= 1) sum += __shfl_down(sum, off);
    if (lane == 0) redbuf[wave] = sum;
    __syncthreads();
    if (tid == 0) {
        float s = 0.0f;
        #pragma unroll
        for (int w = 0; w < BLOCK / 64; ++w) s += redbuf[w];
        partial[blockIdx.x] = s;
    }
}

__global__ __launch_bounds__(BLOCK) void rmse_finalize_kernel(
    const float* __restrict__ partial, int nPartial, float* __restrict__ out, int N)
{
    __shared__ float redbuf[BLOCK / 64];
    float sum = 0.0f;
    for (int i = threadIdx.x; i < nPartial; i += BLOCK) sum += partial[i];
    #pragma unroll
    for (int off = 32; off > 0; off >>= 1) sum += __shfl_down(sum, off);
    const int lane = threadIdx.x & 63;
    const int wave = threadIdx.x >> 6;
    if (lane == 0) redbuf[wave] = sum;
    __syncthreads();
    if (threadIdx.x == 0) {
        float s = 0.0f;
        #pragma unroll
        for (int w = 0; w < BLOCK / 64; ++w) s += redbuf[w];
        out[0] = sqrtf(s / (float)N) + 1e-8f;
    }
}

extern "C" void kernel_launch(void* const* d_in, const int* in_sizes, int n_in,
                              void* d_out, int out_size, void* d_ws, size_t ws_size,
                              hipStream_t stream) {
    const float* rot_kf  = (const float*)d_in[0];
    const float* pose_kf = (const float*)d_in[1];
    const float* rot_gt  = (const float*)d_in[2];
    const float* pose_gt = (const float*)d_in[3];
    float* out = (float*)d_out;
    float* partial = (float*)d_ws;

    const int N = in_sizes[1] / 3;   // pose_kf is [N,3]
    const int nChunks = (int)(((long long)N + FPC - 1) / FPC);

    int grid = (nChunks + 1) / 2;    // ~2 chunks per block, balanced
    if (grid > MAXBLOCKS) grid = MAXBLOCKS;
    const int wsCap = (int)(ws_size / sizeof(float));
    if (grid > wsCap) grid = wsCap;
    if (grid < 1) grid = 1;

    rmse_partial_kernel<<<grid, BLOCK, 0, stream>>>(rot_kf, pose_kf, rot_gt, pose_gt, partial, N);
    rmse_finalize_kernel<<<1, BLOCK, 0, stream>>>(partial, grid, out, N);
}